// Round 5
// baseline (15.980 us; speedup 1.0000x reference)
//
#include <hip/hip_runtime.h>

#define NPATCH 196
#define BATCH  8192
#define NPAIR  (BATCH * NPATCH / 2)   // patch pairs (2 adjacent patches each)
#define QTR    (NPAIR / 4)            // each thread does pairs u, u+QTR, u+2*QTR, u+3*QTR

typedef float f4 __attribute__((ext_vector_type(4)));

// Analytic solution of the 4-qubit circuit (Heisenberg picture):
//   z0 = cos(p0) cos(t0)
//   z1 = cos(p0) cos(t0) cos(t1+p1)
//   z2 = z1 * [cos(p4) cos(t2) + sin(p4) sin(p2) sin(t2) sin(t3+p3)]
//   z3 = cos(t2) cos(t3+p3)
// (t0..t3) = (TL, TR, BL, BR) pixels of the 2x2 patch. Exact.
__global__ __launch_bounds__(256) void quanv_kernel(
    const float* __restrict__ x,   // [B, 784]
    const float* __restrict__ rp,  // [5]
    f4* __restrict__ out)          // [B*196] f4 = [B, 784]
{
    int u = blockIdx.x * 256 + threadIdx.x;
    if (u >= QTR) return;

    // pair index -> load base: 98 pairs/image, 7 pairs per patch-row
    auto base_of = [](int n2) {
        int b   = n2 / 98;
        int r   = n2 - b * 98;
        int pi  = r / 7;
        int pjp = r - pi * 7;
        return b * 784 + pi * 56 + pjp * 4;   // 16B-aligned
    };

    int b0 = base_of(u);
    int b1 = base_of(u + QTR);
    int b2 = base_of(u + 2 * QTR);
    int b3 = base_of(u + 3 * QTR);

    // Issue all 8 independent 16B loads before any compute (max MLP).
    f4 top0 = __builtin_nontemporal_load((const f4*)(x + b0));
    f4 bot0 = __builtin_nontemporal_load((const f4*)(x + b0 + 28));
    f4 top1 = __builtin_nontemporal_load((const f4*)(x + b1));
    f4 bot1 = __builtin_nontemporal_load((const f4*)(x + b1 + 28));
    f4 top2 = __builtin_nontemporal_load((const f4*)(x + b2));
    f4 bot2 = __builtin_nontemporal_load((const f4*)(x + b2 + 28));
    f4 top3 = __builtin_nontemporal_load((const f4*)(x + b3));
    f4 bot3 = __builtin_nontemporal_load((const f4*)(x + b3 + 28));

    // uniform circuit constants
    float p1 = rp[1], p3 = rp[3];
    float K0  = __cosf(rp[0]);
    float K4  = __cosf(rp[4]);
    float K24 = __sinf(rp[4]) * __sinf(rp[2]);

    #define PATCH(T0, T1, B0, B1, O) {                      \
        float ct0 = __cosf(T0);                             \
        float c1  = __cosf((T1) + p1);                      \
        float st2, ct2; __sincosf((B0), &st2, &ct2);        \
        float s3, c3;   __sincosf((B1) + p3, &s3, &c3);     \
        float z0 = K0 * ct0;                                \
        float z1 = z0 * c1;                                 \
        float z2 = z1 * (K4 * ct2 + K24 * st2 * s3);        \
        float z3 = ct2 * c3;                                \
        O = (f4){z0, z1, z2, z3}; }

    f4 oA, oB;
    #define DO_UNIT(TOP, BOT, IDX) {                                 \
        PATCH(TOP.x, TOP.y, BOT.x, BOT.y, oA)                        \
        PATCH(TOP.z, TOP.w, BOT.z, BOT.w, oB)                        \
        __builtin_nontemporal_store(oA, out + (size_t)2 * (IDX));    \
        __builtin_nontemporal_store(oB, out + (size_t)2 * (IDX) + 1); }

    DO_UNIT(top0, bot0, u)
    DO_UNIT(top1, bot1, u + QTR)
    DO_UNIT(top2, bot2, u + 2 * QTR)
    DO_UNIT(top3, bot3, u + 3 * QTR)

    #undef DO_UNIT
    #undef PATCH
}

extern "C" void kernel_launch(void* const* d_in, const int* in_sizes, int n_in,
                              void* d_out, int out_size, void* d_ws, size_t ws_size,
                              hipStream_t stream) {
    const float* x  = (const float*)d_in[0];
    const float* rp = (const float*)d_in[1];
    f4* out = (f4*)d_out;
    int blocks = (QTR + 255) / 256;
    quanv_kernel<<<blocks, 256, 0, stream>>>(x, rp, out);
}

// Round 6
// 15.395 us; speedup vs baseline: 1.0380x; 1.0380x over previous
//
#include <hip/hip_runtime.h>

#define NPATCH 196
#define BATCH  8192
#define NPAIR  (BATCH * NPATCH / 2)   // patch pairs (2 adjacent patches each)
#define QTR    (NPAIR / 4)            // each thread does pairs u, u+QTR, u+2*QTR, u+3*QTR

typedef float f4 __attribute__((ext_vector_type(4)));

// Analytic solution of the 4-qubit circuit (Heisenberg picture):
//   z0 = cos(p0) cos(t0)
//   z1 = cos(p0) cos(t0) cos(t1+p1)
//   z2 = z1 * [cos(p4) cos(t2) + sin(p4) sin(p2) sin(t2) sin(t3+p3)]
//   z3 = cos(t2) cos(t3+p3)
// (t0..t3) = (TL, TR, BL, BR) pixels of the 2x2 patch. Exact.
__global__ __launch_bounds__(256) void quanv_kernel(
    const float* __restrict__ x,   // [B, 784]
    const float* __restrict__ rp,  // [5]
    f4* __restrict__ out)          // [B*196] f4 = [B, 784]
{
    int u = blockIdx.x * 256 + threadIdx.x;
    if (u >= QTR) return;

    // pair index -> load base: 98 pairs/image, 7 pairs per patch-row
    auto base_of = [](int n2) {
        int b   = n2 / 98;
        int r   = n2 - b * 98;
        int pi  = r / 7;
        int pjp = r - pi * 7;
        return b * 784 + pi * 56 + pjp * 4;   // 16B-aligned
    };

    int b0 = base_of(u);
    int b1 = base_of(u + QTR);
    int b2 = base_of(u + 2 * QTR);
    int b3 = base_of(u + 3 * QTR);

    // Issue all 8 independent 16B loads before any compute (max MLP).
    // Plain cached loads: L2 must absorb the 64B-line sharing between the
    // top/bot runs of adjacent patch-rows (224B rows are not 64B-aligned).
    f4 top0 = *(const f4*)(x + b0);
    f4 bot0 = *(const f4*)(x + b0 + 28);
    f4 top1 = *(const f4*)(x + b1);
    f4 bot1 = *(const f4*)(x + b1 + 28);
    f4 top2 = *(const f4*)(x + b2);
    f4 bot2 = *(const f4*)(x + b2 + 28);
    f4 top3 = *(const f4*)(x + b3);
    f4 bot3 = *(const f4*)(x + b3 + 28);

    // uniform circuit constants
    float p1 = rp[1], p3 = rp[3];
    float K0  = __cosf(rp[0]);
    float K4  = __cosf(rp[4]);
    float K24 = __sinf(rp[4]) * __sinf(rp[2]);

    #define PATCH(T0, T1, B0, B1, O) {                      \
        float ct0 = __cosf(T0);                             \
        float c1  = __cosf((T1) + p1);                      \
        float st2, ct2; __sincosf((B0), &st2, &ct2);        \
        float s3, c3;   __sincosf((B1) + p3, &s3, &c3);     \
        float z0 = K0 * ct0;                                \
        float z1 = z0 * c1;                                 \
        float z2 = z1 * (K4 * ct2 + K24 * st2 * s3);        \
        float z3 = ct2 * c3;                                \
        O = (f4){z0, z1, z2, z3}; }

    f4 oA, oB;
    #define DO_UNIT(TOP, BOT, IDX) {                                 \
        PATCH(TOP.x, TOP.y, BOT.x, BOT.y, oA)                        \
        PATCH(TOP.z, TOP.w, BOT.z, BOT.w, oB)                        \
        __builtin_nontemporal_store(oA, out + (size_t)2 * (IDX));    \
        __builtin_nontemporal_store(oB, out + (size_t)2 * (IDX) + 1); }

    DO_UNIT(top0, bot0, u)
    DO_UNIT(top1, bot1, u + QTR)
    DO_UNIT(top2, bot2, u + 2 * QTR)
    DO_UNIT(top3, bot3, u + 3 * QTR)

    #undef DO_UNIT
    #undef PATCH
}

extern "C" void kernel_launch(void* const* d_in, const int* in_sizes, int n_in,
                              void* d_out, int out_size, void* d_ws, size_t ws_size,
                              hipStream_t stream) {
    const float* x  = (const float*)d_in[0];
    const float* rp = (const float*)d_in[1];
    f4* out = (f4*)d_out;
    int blocks = (QTR + 255) / 256;
    quanv_kernel<<<blocks, 256, 0, stream>>>(x, rp, out);
}